// Round 8
// baseline (112.226 us; speedup 1.0000x reference)
//
#include <hip/hip_runtime.h>
#include <math.h>

#define BB 2
#define TT 2048
#define CC 1024
#define HH 16
#define DD 64
#define WINW 256

constexpr int MROWS  = BB * TT;    // 4096
constexpr int NQKV   = 3 * CC;     // 3072
constexpr int QKV_LD = 3 * CC;     // qkv row stride (elems)

typedef unsigned short ushort_t;
typedef __attribute__((ext_vector_type(8))) short  bf16x8;
typedef __attribute__((ext_vector_type(4))) float  f32x4;
typedef __attribute__((ext_vector_type(8))) unsigned short u16x8;

__device__ __forceinline__ float bf2f(ushort_t u) {
    return __uint_as_float(((unsigned int)u) << 16);
}
__device__ __forceinline__ ushort_t f2bf(float f) {
    unsigned int u = __float_as_uint(f);
    u += 0x7fffu + ((u >> 16) & 1u);      // RNE
    return (ushort_t)(u >> 16);
}

__device__ __forceinline__ void async16(void* lds, const void* g) {
    __builtin_amdgcn_global_load_lds(
        (const __attribute__((address_space(1))) unsigned int*)g,
        (__attribute__((address_space(3))) unsigned int*)lds, 16, 0, 0);
}

// ln(10000)/32
#define ROPE_LN 0.2878231366242557f

// ---------------------------------------------------------------------------
// One fused f32 -> bf16 conversion for x, w_qkv, w_out. 4 elems/thread.
// ---------------------------------------------------------------------------
constexpr int NX = MROWS * CC;     // 4,194,304
constexpr int NQ = NQKV * CC;      // 3,145,728
constexpr int NO = CC * CC;        // 1,048,576

__global__ __launch_bounds__(256)
void convert_all(const float* __restrict__ x, const float* __restrict__ wq,
                 const float* __restrict__ wo, ushort_t* __restrict__ xb,
                 ushort_t* __restrict__ wqb, ushort_t* __restrict__ wob) {
    int i = (blockIdx.x * 256 + threadIdx.x) * 4;
    const float* src;
    ushort_t* dst;
    if (i < NX)           { src = x  + i;             dst = xb  + i; }
    else if (i < NX + NQ) { src = wq + (i - NX);      dst = wqb + (i - NX); }
    else                  { src = wo + (i - NX - NQ); dst = wob + (i - NX - NQ); }
    float4 v = *(const float4*)src;
    ushort4 o;
    o.x = f2bf(v.x); o.y = f2bf(v.y); o.z = f2bf(v.z); o.w = f2bf(v.w);
    *(ushort4*)dst = o;
}

// ---------------------------------------------------------------------------
// GEMM1: 256x256 tile, BK=64, 8 waves (2Mx4N), 8-phase counted-vmcnt.
// At K=1024 this structure's verified rate is ~848 TF (m248v2); with 192/256
// CU coverage the chip rate is ~640 TF. This revision hoists the mh==1
// phases' ds_reads ABOVE the entry barrier (data already vmcnt-guaranteed by
// the mh==0 phase) so read latency hides under the barrier wait (m201's
// read-before-barrier pattern), and drops the post-barrier sched_barrier(0).
// ---------------------------------------------------------------------------
__global__ __launch_bounds__(512)
void gemm1_8phase(const ushort_t* __restrict__ A, const ushort_t* __restrict__ Bw,
                  ushort_t* __restrict__ Cc) {
    constexpr int K = 1024, N = 3072, NT = 16;   // NT = K/64
    __shared__ __align__(16) ushort_t As[2][2][256 * 32];   // [dbuf][khalf] 64 KB
    __shared__ __align__(16) ushort_t Bs[2][2][256 * 32];   // 64 KB

    const int tid  = threadIdx.x;
    const int lane = tid & 63;
    const int w    = tid >> 6;
    const int wm   = w >> 2;            // 0..1 -> 128 rows
    const int wn   = w & 3;             // 0..3 -> 64 cols
    const int fr   = lane & 15;
    const int fq   = lane >> 4;

    // XCD-aware bijective swizzle of the 192-block grid
    const int nbx = NQKV / 256;                       // 12
    int flat = blockIdx.y * nbx + blockIdx.x;         // 0..191
    flat = (flat & 7) * 24 + (flat >> 3);             // 8 XCDs x 24 chunks
    const int bm = (flat / nbx) * 256;
    const int bn = (flat % nbx) * 256;

    // staging: thread covers row sr (of 128), 16B col-block dcb;
    // source col-block = dcb ^ ((sr>>1)&3)  (involution)
    const int sr  = tid >> 2;           // 0..127
    const int dcb = tid & 3;
    const int scb = dcb ^ ((sr >> 1) & 3);

    // fragment-read swizzle: same involution keyed by the row being read
    const int cbr = fq ^ ((fr >> 1) & 3);

    f32x4 acc[8][4];
#pragma unroll
    for (int m = 0; m < 8; ++m)
#pragma unroll
        for (int n = 0; n < 4; ++n)
            acc[m][n] = f32x4{0.f, 0.f, 0.f, 0.f};

    // ---- prologue: stage tile 0 into dbuf 0, parts A_k0,B_k0,A_k1,B_k1 ----
#pragma unroll
    for (int p = 0; p < 4; ++p) {
        const int skh = p >> 1;
        const bool isB = p & 1;
        const ushort_t* G = isB ? Bw : A;
        const int br = isB ? bn : bm;
        ushort_t* L = isB ? &Bs[0][skh][0] : &As[0][skh][0];
#pragma unroll
        for (int hh = 0; hh < 2; ++hh)
            async16(&L[(hh * 128 + sr) * 32 + dcb * 8],
                    G + (size_t)(br + hh * 128 + sr) * K + skh * 32 + scb * 8);
    }

    for (int t = 0; t < NT; ++t) {
        const int d  = t & 1;
        const int tn = (t + 1) & (NT - 1);   // wraps at tail (uniform counts)
        bf16x8 bfr[4];

#pragma unroll
        for (int ph = 0; ph < 4; ++ph) {
            const int kh = ph >> 1;     // compute k-half of tile t
            const int mh = ph & 1;      // compute m-half of wave's rows

            // ---- stage part ph of tile tn into dbuf d^1 ----
            {
                const int skh = ph >> 1;
                const bool isB = ph & 1;
                const ushort_t* G = isB ? Bw : A;
                const int br = isB ? bn : bm;
                ushort_t* L = isB ? &Bs[d ^ 1][skh][0] : &As[d ^ 1][skh][0];
#pragma unroll
                for (int hh = 0; hh < 2; ++hh)
                    async16(&L[(hh * 128 + sr) * 32 + dcb * 8],
                            G + (size_t)(br + hh * 128 + sr) * K
                              + (size_t)tn * 64 + skh * 32 + scb * 8);
            }

            bf16x8 afr[4];
            if (mh == 1) {
                // hoisted reads: As[d][kh] fully landed since the kh-entry
                // barrier (mh==0 phase); latency hides under this barrier
#pragma unroll
                for (int i = 0; i < 4; ++i) {
                    const int ra = wm * 128 + (4 + i) * 16 + fr;
                    afr[i] = *(const bf16x8*)&As[d][kh][ra * 32 + cbr * 8];
                }
            } else {
                // counted wait at kh entry: oldest 2-load pair must land;
                // 3 newer pairs (6 loads) stay in flight
                asm volatile("s_waitcnt vmcnt(6)" ::: "memory");
            }
            __builtin_amdgcn_s_barrier();

            if (mh == 0) {
#pragma unroll
                for (int n = 0; n < 4; ++n) {
                    const int rb = wn * 64 + n * 16 + fr;
                    bfr[n] = *(const bf16x8*)&Bs[d][kh][rb * 32 + cbr * 8];
                }
#pragma unroll
                for (int i = 0; i < 4; ++i) {
                    const int ra = wm * 128 + i * 16 + fr;
                    afr[i] = *(const bf16x8*)&As[d][kh][ra * 32 + cbr * 8];
                }
            }

            __builtin_amdgcn_s_setprio(1);
#pragma unroll
            for (int i = 0; i < 4; ++i)
#pragma unroll
                for (int n = 0; n < 4; ++n)
                    acc[mh * 4 + i][n] = __builtin_amdgcn_mfma_f32_16x16x32_bf16(
                        afr[i], bfr[n], acc[mh * 4 + i][n], 0, 0, 0);
            __builtin_amdgcn_s_setprio(0);
            // end-of-phase barrier (tile-boundary safety: all LDS reads done
            // before anyone stages into a buffer being read)
            __builtin_amdgcn_s_barrier();
        }
    }

    // ---- epilogue ----
#pragma unroll
    for (int m = 0; m < 8; ++m)
#pragma unroll
        for (int n = 0; n < 4; ++n)
#pragma unroll
            for (int j = 0; j < 4; ++j) {
                const int row = bm + wm * 128 + m * 16 + fq * 4 + j;
                const int col = bn + wn * 64 + n * 16 + fr;
                Cc[(size_t)row * N + col] = f2bf(acc[m][n][j]);
            }
}

// ---------------------------------------------------------------------------
// bf16 MFMA GEMM (m97 structure) — GEMM2 (N=1024 -> 256 blocks), + XCD swizzle.
// ---------------------------------------------------------------------------
template <bool BIAS, bool OUT_BF16>
__global__ __launch_bounds__(256)
void gemm_nt_mfma(const ushort_t* __restrict__ A, const ushort_t* __restrict__ Bw,
                  const float* __restrict__ bias, void* __restrict__ Cc,
                  int M, int N, int K) {
    __shared__ __align__(16) ushort_t As[128 * 32];
    __shared__ __align__(16) ushort_t Bs[128 * 32];

    const int tid  = threadIdx.x;
    const int lane = tid & 63;
    const int wv   = tid >> 6;
    const int wr   = wv >> 1;
    const int wc   = wv & 1;

    // XCD-aware bijective swizzle (grid size is a multiple of 8 here: 256)
    const int nbx = gridDim.x;
    const int nwg = nbx * gridDim.y;
    int flat = blockIdx.y * nbx + blockIdx.x;
    flat = (flat & 7) * (nwg >> 3) + (flat >> 3);
    const int bm = (flat / nbx) * 128;
    const int bn = (flat % nbx) * 128;

    const int srow = tid >> 2;
    const int scol = (tid & 3) * 8;

    const ushort_t* Ag = A + (size_t)(bm + srow) * K + scol;
    const ushort_t* Bg = Bw + (size_t)(bn + srow) * K + scol;

    f32x4 acc[4][4];
#pragma unroll
    for (int m = 0; m < 4; ++m)
#pragma unroll
        for (int n = 0; n < 4; ++n)
            acc[m][n] = f32x4{0.f, 0.f, 0.f, 0.f};

    const int fr = lane & 15;
    const int fq = lane >> 4;

    for (int k0 = 0; k0 < K; k0 += 32) {
        async16(&As[tid * 8],        Ag);
        async16(&As[2048 + tid * 8], Ag + (size_t)64 * K);
        async16(&Bs[tid * 8],        Bg);
        async16(&Bs[2048 + tid * 8], Bg + (size_t)64 * K);
        Ag += 32; Bg += 32;
        __syncthreads();

        bf16x8 af[4], bfv[4];
#pragma unroll
        for (int m = 0; m < 4; ++m)
            af[m] = *(const bf16x8*)&As[(wr * 64 + m * 16 + fr) * 32 + fq * 8];
#pragma unroll
        for (int n = 0; n < 4; ++n)
            bfv[n] = *(const bf16x8*)&Bs[(wc * 64 + n * 16 + fr) * 32 + fq * 8];
#pragma unroll
        for (int m = 0; m < 4; ++m)
#pragma unroll
            for (int n = 0; n < 4; ++n)
                acc[m][n] = __builtin_amdgcn_mfma_f32_16x16x32_bf16(
                    af[m], bfv[n], acc[m][n], 0, 0, 0);
        __syncthreads();
    }

#pragma unroll
    for (int m = 0; m < 4; ++m) {
#pragma unroll
        for (int n = 0; n < 4; ++n) {
            const int col = bn + wc * 64 + n * 16 + fr;
            const float bv = BIAS ? bias[col] : 0.0f;
#pragma unroll
            for (int j = 0; j < 4; ++j) {
                const int row = bm + wr * 64 + m * 16 + fq * 4 + j;
                float v = acc[m][n][j] + bv;
                if (OUT_BF16)
                    ((ushort_t*)Cc)[(size_t)row * N + col] = f2bf(v);
                else
                    ((float*)Cc)[(size_t)row * N + col] = v;
            }
        }
    }
}

// ---------------------------------------------------------------------------
// MFMA windowed flash attention, v3 + per-wave tile skip.
// A wave's 16 q-rows overlap only ~5 of the block's 6 K-tiles; skip the
// QK/softmax/PV work on non-overlapping tiles (wave-uniform branch).
// Cooperative parts (K staging, V transpose, barriers) always execute.
// ---------------------------------------------------------------------------
#define MASKNEG (-1e30f)

__global__ __launch_bounds__(512)
void attn_mfma(const ushort_t* __restrict__ qkv, ushort_t* __restrict__ out) {
    __shared__ __align__(16) ushort_t Ks[2][64 * 64];
    __shared__ __align__(16) ushort_t Vlin[2][64 * 64];
    __shared__ __align__(16) ushort_t Vt[64 * 72];
    __shared__ __align__(16) ushort_t Ps[8][16 * 72];

    const int tid  = threadIdx.x;
    const int lane = tid & 63;
    const int w    = tid >> 6;
    const int fr   = lane & 15;
    const int fq   = lane >> 4;

    const int blk = blockIdx.x;
    const int qt  = blk & 15;
    const int h   = (blk >> 4) & 15;
    const int b   = blk >> 8;
    const int q0  = qt * 128;

    const ushort_t* base = qkv + (size_t)(b * TT) * QKV_LD + h * (3 * DD);

    const int srow = tid >> 3;
    const int cbs  = (tid & 7) ^ (srow & 7);

    float thK[4];
#pragma unroll
    for (int e = 0; e < 4; ++e)
        thK[e] = __expf(-ROPE_LN * (float)(cbs * 4 + e));

    bf16x8 qf0, qf1;
    {
        const int tq = q0 + w * 16 + fr;
        const ushort_t* qrow = base + (size_t)tq * QKV_LD;
        u16x8 r0 = *(const u16x8*)(qrow + fq * 8);
        u16x8 r1 = *(const u16x8*)(qrow + 32 + fq * 8);
        const float tf = (float)tq;
#pragma unroll
        for (int e = 0; e < 4; ++e) {
            float th0 = __expf(-ROPE_LN * (float)(fq * 4 + e));
            float a0 = tf * th0;
            float s0 = __sinf(a0), c0 = __cosf(a0);
            float x1 = bf2f(r0[2 * e]), x2 = bf2f(r0[2 * e + 1]);
            r0[2 * e]     = f2bf(x1 * c0 - x2 * s0);
            r0[2 * e + 1] = f2bf(x1 * s0 + x2 * c0);
            float th1 = __expf(-ROPE_LN * (float)(16 + fq * 4 + e));
            float a1 = tf * th1;
            float s1 = __sinf(a1), c1 = __cosf(a1);
            float y1 = bf2f(r1[2 * e]), y2 = bf2f(r1[2 * e + 1]);
            r1[2 * e]     = f2bf(y1 * c1 - y2 * s1);
            r1[2 * e + 1] = f2bf(y1 * s1 + y2 * c1);
        }
        qf0 = *(bf16x8*)&r0;
        qf1 = *(bf16x8*)&r1;
    }

    f32x4 oacc[4];
#pragma unroll
    for (int nd = 0; nd < 4; ++nd) oacc[nd] = f32x4{0.f, 0.f, 0.f, 0.f};
    float mj[4], lj[4];
#pragma unroll
    for (int j = 0; j < 4; ++j) { mj[j] = MASKNEG; lj[j] = 0.f; }

    const int kstart = (q0 >= WINW) ? (q0 - WINW) : 0;
    const int ntiles = (q0 + 128 - kstart) >> 6;
    const int qlo = q0 + w * 16;               // wave's q-range [qlo, qlo+15]

    {
        const ushort_t* src = base + (size_t)(kstart + srow) * QKV_LD + DD + cbs * 8;
        u16x8 kv = *(const u16x8*)src;
        const float tf = (float)(kstart + srow);
#pragma unroll
        for (int e = 0; e < 4; ++e) {
            float a = tf * thK[e];
            float s = __sinf(a), c = __cosf(a);
            float x1 = bf2f(kv[2 * e]), x2 = bf2f(kv[2 * e + 1]);
            kv[2 * e]     = f2bf(x1 * c - x2 * s);
            kv[2 * e + 1] = f2bf(x1 * s + x2 * c);
        }
        *(u16x8*)&Ks[0][tid * 8] = kv;
        async16(&Vlin[0][tid * 8], src + DD);
    }
    __syncthreads();

    int cur = 0;
    for (int t = 0; t < ntiles; ++t) {
        const int kt0 = kstart + t * 64;
        const bool pf = (t + 1 < ntiles);
        // wave-uniform: does this tile overlap [qlo-WINW, qlo+15]?
        const bool act = (kt0 <= qlo + 15) && (kt0 + 63 >= qlo - WINW);

        u16x8 kpre;
        if (pf) {
            const ushort_t* src =
                base + (size_t)(kt0 + 64 + srow) * QKV_LD + DD + cbs * 8;
            kpre = *(const u16x8*)src;
            async16(&Vlin[cur ^ 1][tid * 8], src + DD);
        }

        {
            u16x8 vv = *(const u16x8*)&Vlin[cur][lane * 64 + ((w ^ (lane & 7)) * 8)];
#pragma unroll
            for (int e = 0; e < 8; ++e)
                Vt[(w * 8 + e) * 72 + lane] = vv[e];
        }

        if (act) {
            f32x4 s[4];
#pragma unroll
            for (int n = 0; n < 4; ++n) {
                const int krow = n * 16 + fr;
                bf16x8 kb0 = *(const bf16x8*)&Ks[cur][krow * 64 + ((fq ^ (krow & 7)) * 8)];
                bf16x8 kb1 = *(const bf16x8*)&Ks[cur][krow * 64 + (((fq + 4) ^ (krow & 7)) * 8)];
                f32x4 z = f32x4{0.f, 0.f, 0.f, 0.f};
                z = __builtin_amdgcn_mfma_f32_16x16x32_bf16(qf0, kb0, z, 0, 0, 0);
                s[n] = __builtin_amdgcn_mfma_f32_16x16x32_bf16(qf1, kb1, z, 0, 0, 0);
            }

            float pmax[4];
#pragma unroll
            for (int j = 0; j < 4; ++j) pmax[j] = MASKNEG;
#pragma unroll
            for (int n = 0; n < 4; ++n) {
                const int key = kt0 + n * 16 + fr;
#pragma unroll
                for (int j = 0; j < 4; ++j) {
                    const int qi = qlo + fq * 4 + j;
                    const bool ok = (key <= qi) && (key >= qi - WINW);
                    float sv = ok ? s[n][j] * 0.125f : MASKNEG;
                    s[n][j] = sv;
                    pmax[j] = fmaxf(pmax[j], sv);
                }
            }
#pragma unroll
            for (int off = 1; off < 16; off <<= 1)
#pragma unroll
                for (int j = 0; j < 4; ++j)
                    pmax[j] = fmaxf(pmax[j], __shfl_xor(pmax[j], off));

            float tl[4] = {0.f, 0.f, 0.f, 0.f};
#pragma unroll
            for (int j = 0; j < 4; ++j) {
                float mnew = fmaxf(mj[j], pmax[j]);
                float alpha = (mnew <= -1e29f) ? 1.0f : __expf(mj[j] - mnew);
                mj[j] = mnew;
                lj[j] *= alpha;
#pragma unroll
                for (int nd = 0; nd < 4; ++nd) oacc[nd][j] *= alpha;
            }
#pragma unroll
            for (int n = 0; n < 4; ++n) {
#pragma unroll
                for (int j = 0; j < 4; ++j) {
                    float sv = s[n][j];
                    float p = (sv <= -1e29f) ? 0.f : __expf(sv - mj[j]);
                    tl[j] += p;
                    Ps[w][(fq * 4 + j) * 72 + n * 16 + fr] = f2bf(p);
                }
            }
#pragma unroll
            for (int off = 1; off < 16; off <<= 1)
#pragma unroll
                for (int j = 0; j < 4; ++j)
                    tl[j] += __shfl_xor(tl[j], off);
#pragma unroll
            for (int j = 0; j < 4; ++j) lj[j] += tl[j];
        }

        if (pf) {
            const float tf = (float)(kt0 + 64 + srow);
#pragma unroll
            for (int e = 0; e < 4; ++e) {
                float a = tf * thK[e];
                float s2 = __sinf(a), c2 = __cosf(a);
                float x1 = bf2f(kpre[2 * e]), x2 = bf2f(kpre[2 * e + 1]);
                kpre[2 * e]     = f2bf(x1 * c2 - x2 * s2);
                kpre[2 * e + 1] = f2bf(x1 * s2 + x2 * c2);
            }
            *(u16x8*)&Ks[cur ^ 1][tid * 8] = kpre;
        }

        __syncthreads();

        if (act) {
            bf16x8 pa0 = *(const bf16x8*)&Ps[w][fr * 72 + fq * 8];
            bf16x8 pa1 = *(const bf16x8*)&Ps[w][fr * 72 + 32 + fq * 8];
#pragma unroll
            for (int nd = 0; nd < 4; ++nd) {
                bf16x8 vb0 = *(const bf16x8*)&Vt[(nd * 16 + fr) * 72 + fq * 8];
                bf16x8 vb1 = *(const bf16x8*)&Vt[(nd * 16 + fr) * 72 + 32 + fq * 8];
                oacc[nd] = __builtin_amdgcn_mfma_f32_16x16x32_bf16(pa0, vb0, oacc[nd], 0, 0, 0);
                oacc[nd] = __builtin_amdgcn_mfma_f32_16x16x32_bf16(pa1, vb1, oacc[nd], 0, 0, 0);
            }
        }

        __syncthreads();
        cur ^= 1;
    }

#pragma unroll
    for (int nd = 0; nd < 4; ++nd) {
#pragma unroll
        for (int j = 0; j < 4; ++j) {
            const int qi = qlo + fq * 4 + j;
            out[(size_t)(b * TT + qi) * CC + h * DD + nd * 16 + fr] =
                f2bf(oacc[nd][j] / lj[j]);
        }
    }
}

// ---------------------------------------------------------------------------
extern "C" void kernel_launch(void* const* d_in, const int* in_sizes, int n_in,
                              void* d_out, int out_size, void* d_ws, size_t ws_size,
                              hipStream_t stream) {
    const float* x     = (const float*)d_in[0];
    const float* w_qkv = (const float*)d_in[1];
    const float* w_out = (const float*)d_in[2];
    const float* b_out = (const float*)d_in[3];
    float* out = (float*)d_out;

    ushort_t* qkv_b  = (ushort_t*)d_ws;
    ushort_t* attn_b = qkv_b  + (size_t)MROWS * NQKV;
    ushort_t* xb     = attn_b + (size_t)MROWS * CC;
    ushort_t* wqb    = xb     + (size_t)MROWS * CC;
    ushort_t* wob    = wqb    + (size_t)NQKV * CC;

    // 0) one fused conversion pass
    convert_all<<<(NX + NQ + NO) / 1024, 256, 0, stream>>>(
        x, w_qkv, w_out, xb, wqb, wob);

    // 1) qkv = x @ w_qkv^T (bf16 out) — 8-phase 256^2 schedule
    gemm1_8phase<<<dim3(NQKV / 256, MROWS / 256), 512, 0, stream>>>(
        xb, wqb, qkv_b);

    // 2) windowed attention with fused RoPE -> attn_b
    attn_mfma<<<BB * HH * (TT / 128), 512, 0, stream>>>(qkv_b, attn_b);

    // 3) out = attn @ w_out^T + b_out  (fp32 out) — m97 structure + swizzle
    gemm_nt_mfma<true, false><<<dim3(CC / 128, MROWS / 128), 256, 0, stream>>>(
        attn_b, wob, b_out, out, MROWS, CC, CC);
}

// Round 10
// 103.966 us; speedup vs baseline: 1.0794x; 1.0794x over previous
//
#include <hip/hip_runtime.h>
#include <math.h>

#define BB 2
#define TT 2048
#define CC 1024
#define HH 16
#define DD 64
#define WINW 256

constexpr int MROWS  = BB * TT;    // 4096
constexpr int NQKV   = 3 * CC;     // 3072
constexpr int QKV_LD = 3 * CC;     // qkv row stride (elems)

typedef unsigned short ushort_t;
typedef __attribute__((ext_vector_type(8))) short  bf16x8;
typedef __attribute__((ext_vector_type(4))) float  f32x4;
typedef __attribute__((ext_vector_type(8))) unsigned short u16x8;

__device__ __forceinline__ float bf2f(ushort_t u) {
    return __uint_as_float(((unsigned int)u) << 16);
}
__device__ __forceinline__ ushort_t f2bf(float f) {
    unsigned int u = __float_as_uint(f);
    u += 0x7fffu + ((u >> 16) & 1u);      // RNE
    return (ushort_t)(u >> 16);
}

__device__ __forceinline__ void async16(void* lds, const void* g) {
    __builtin_amdgcn_global_load_lds(
        (const __attribute__((address_space(1))) unsigned int*)g,
        (__attribute__((address_space(3))) unsigned int*)lds, 16, 0, 0);
}

// ln(10000)/32
#define ROPE_LN 0.2878231366242557f

// ---------------------------------------------------------------------------
// One fused f32 -> bf16 conversion for x, w_qkv, w_out. 4 elems/thread.
// ---------------------------------------------------------------------------
constexpr int NX = MROWS * CC;     // 4,194,304
constexpr int NQ = NQKV * CC;      // 3,145,728
constexpr int NO = CC * CC;        // 1,048,576

__global__ __launch_bounds__(256)
void convert_all(const float* __restrict__ x, const float* __restrict__ wq,
                 const float* __restrict__ wo, ushort_t* __restrict__ xb,
                 ushort_t* __restrict__ wqb, ushort_t* __restrict__ wob) {
    int i = (blockIdx.x * 256 + threadIdx.x) * 4;
    const float* src;
    ushort_t* dst;
    if (i < NX)           { src = x  + i;             dst = xb  + i; }
    else if (i < NX + NQ) { src = wq + (i - NX);      dst = wqb + (i - NX); }
    else                  { src = wo + (i - NX - NQ); dst = wob + (i - NX - NQ); }
    float4 v = *(const float4*)src;
    ushort4 o;
    o.x = f2bf(v.x); o.y = f2bf(v.y); o.z = f2bf(v.z); o.w = f2bf(v.w);
    *(ushort4*)dst = o;
}

// ---------------------------------------------------------------------------
// GEMM1: 256x256 tile, BK=64, 8 waves (2Mx4N), 8-phase counted-vmcnt
// (round-7 body = verified 40.5 us). FIX (r10): drain vmcnt(0) after the
// main loop — the uniform-count tail staging leaves ~8 global_load_lds in
// flight at s_endpgm; LDS-DMA has no register result so the compiler emits
// no wait, and the loads can land after workgroup teardown into LDS
// re-assigned to a successor block (the r9 post-timing nondeterminism).
// ---------------------------------------------------------------------------
__global__ __launch_bounds__(512)
void gemm1_8phase(const ushort_t* __restrict__ A, const ushort_t* __restrict__ Bw,
                  ushort_t* __restrict__ Cc) {
    constexpr int K = 1024, N = 3072, NT = 16;   // NT = K/64
    __shared__ __align__(16) ushort_t As[2][2][256 * 32];   // [dbuf][khalf] 64 KB
    __shared__ __align__(16) ushort_t Bs[2][2][256 * 32];   // 64 KB

    const int tid  = threadIdx.x;
    const int lane = tid & 63;
    const int w    = tid >> 6;
    const int wm   = w >> 2;            // 0..1 -> 128 rows
    const int wn   = w & 3;             // 0..3 -> 64 cols
    const int fr   = lane & 15;
    const int fq   = lane >> 4;

    // XCD-aware bijective swizzle of the 192-block grid
    const int nbx = NQKV / 256;                       // 12
    int flat = blockIdx.y * nbx + blockIdx.x;         // 0..191
    flat = (flat & 7) * 24 + (flat >> 3);             // 8 XCDs x 24 chunks
    const int bm = (flat / nbx) * 256;
    const int bn = (flat % nbx) * 256;

    // staging: thread covers row sr (of 128), 16B col-block dcb;
    // source col-block = dcb ^ ((sr>>1)&3)  (involution)
    const int sr  = tid >> 2;           // 0..127
    const int dcb = tid & 3;
    const int scb = dcb ^ ((sr >> 1) & 3);

    // fragment-read swizzle: same involution keyed by the row being read
    const int cbr = fq ^ ((fr >> 1) & 3);

    f32x4 acc[8][4];
#pragma unroll
    for (int m = 0; m < 8; ++m)
#pragma unroll
        for (int n = 0; n < 4; ++n)
            acc[m][n] = f32x4{0.f, 0.f, 0.f, 0.f};

    // ---- prologue: stage tile 0 into dbuf 0, parts A_k0,B_k0,A_k1,B_k1 ----
#pragma unroll
    for (int p = 0; p < 4; ++p) {
        const int skh = p >> 1;
        const bool isB = p & 1;
        const ushort_t* G = isB ? Bw : A;
        const int br = isB ? bn : bm;
        ushort_t* L = isB ? &Bs[0][skh][0] : &As[0][skh][0];
#pragma unroll
        for (int hh = 0; hh < 2; ++hh)
            async16(&L[(hh * 128 + sr) * 32 + dcb * 8],
                    G + (size_t)(br + hh * 128 + sr) * K + skh * 32 + scb * 8);
    }

    for (int t = 0; t < NT; ++t) {
        const int d  = t & 1;
        const int tn = (t + 1) & (NT - 1);   // wraps at tail (uniform counts)
        bf16x8 bfr[4];

#pragma unroll
        for (int ph = 0; ph < 4; ++ph) {
            const int kh = ph >> 1;     // compute k-half of tile t
            const int mh = ph & 1;      // compute m-half of wave's rows

            // ---- stage part ph of tile tn into dbuf d^1 ----
            {
                const int skh = ph >> 1;
                const bool isB = ph & 1;
                const ushort_t* G = isB ? Bw : A;
                const int br = isB ? bn : bm;
                ushort_t* L = isB ? &Bs[d ^ 1][skh][0] : &As[d ^ 1][skh][0];
#pragma unroll
                for (int hh = 0; hh < 2; ++hh)
                    async16(&L[(hh * 128 + sr) * 32 + dcb * 8],
                            G + (size_t)(br + hh * 128 + sr) * K
                              + (size_t)tn * 64 + skh * 32 + scb * 8);
            }

            // ---- counted wait at kh entry: oldest 2-load pair must land;
            //      3 newer pairs (6 loads) stay in flight ----
            if (mh == 0)
                asm volatile("s_waitcnt vmcnt(6)" ::: "memory");
            __builtin_amdgcn_s_barrier();
            __builtin_amdgcn_sched_barrier(0);

            if (mh == 0) {
#pragma unroll
                for (int n = 0; n < 4; ++n) {
                    const int rb = wn * 64 + n * 16 + fr;
                    bfr[n] = *(const bf16x8*)&Bs[d][kh][rb * 32 + cbr * 8];
                }
            }
            bf16x8 afr[4];
#pragma unroll
            for (int i = 0; i < 4; ++i) {
                const int ra = wm * 128 + (mh * 4 + i) * 16 + fr;
                afr[i] = *(const bf16x8*)&As[d][kh][ra * 32 + cbr * 8];
            }

            __builtin_amdgcn_s_setprio(1);
#pragma unroll
            for (int i = 0; i < 4; ++i)
#pragma unroll
                for (int n = 0; n < 4; ++n)
                    acc[mh * 4 + i][n] = __builtin_amdgcn_mfma_f32_16x16x32_bf16(
                        afr[i], bfr[n], acc[mh * 4 + i][n], 0, 0, 0);
            __builtin_amdgcn_s_setprio(0);
            // end-of-phase barrier (tile-boundary safety)
            __builtin_amdgcn_s_barrier();
        }
    }

    // ---- drain in-flight LDS-DMA before teardown (r9 race fix) ----
    asm volatile("s_waitcnt vmcnt(0)" ::: "memory");

    // ---- epilogue ----
#pragma unroll
    for (int m = 0; m < 8; ++m)
#pragma unroll
        for (int n = 0; n < 4; ++n)
#pragma unroll
            for (int j = 0; j < 4; ++j) {
                const int row = bm + wm * 128 + m * 16 + fq * 4 + j;
                const int col = bn + wn * 64 + n * 16 + fr;
                Cc[(size_t)row * N + col] = f2bf(acc[m][n][j]);
            }
}

// ---------------------------------------------------------------------------
// bf16 MFMA GEMM (m97 structure) — GEMM2 (N=1024 -> 256 blocks), + XCD swizzle.
// (final __syncthreads in the k-loop drains vmcnt(0) -> no teardown race)
// ---------------------------------------------------------------------------
template <bool BIAS, bool OUT_BF16>
__global__ __launch_bounds__(256)
void gemm_nt_mfma(const ushort_t* __restrict__ A, const ushort_t* __restrict__ Bw,
                  const float* __restrict__ bias, void* __restrict__ Cc,
                  int M, int N, int K) {
    __shared__ __align__(16) ushort_t As[128 * 32];
    __shared__ __align__(16) ushort_t Bs[128 * 32];

    const int tid  = threadIdx.x;
    const int lane = tid & 63;
    const int wv   = tid >> 6;
    const int wr   = wv >> 1;
    const int wc   = wv & 1;

    // XCD-aware bijective swizzle (grid size is a multiple of 8 here: 256)
    const int nbx = gridDim.x;
    const int nwg = nbx * gridDim.y;
    int flat = blockIdx.y * nbx + blockIdx.x;
    flat = (flat & 7) * (nwg >> 3) + (flat >> 3);
    const int bm = (flat / nbx) * 128;
    const int bn = (flat % nbx) * 128;

    const int srow = tid >> 2;
    const int scol = (tid & 3) * 8;

    const ushort_t* Ag = A + (size_t)(bm + srow) * K + scol;
    const ushort_t* Bg = Bw + (size_t)(bn + srow) * K + scol;

    f32x4 acc[4][4];
#pragma unroll
    for (int m = 0; m < 4; ++m)
#pragma unroll
        for (int n = 0; n < 4; ++n)
            acc[m][n] = f32x4{0.f, 0.f, 0.f, 0.f};

    const int fr = lane & 15;
    const int fq = lane >> 4;

    for (int k0 = 0; k0 < K; k0 += 32) {
        async16(&As[tid * 8],        Ag);
        async16(&As[2048 + tid * 8], Ag + (size_t)64 * K);
        async16(&Bs[tid * 8],        Bg);
        async16(&Bs[2048 + tid * 8], Bg + (size_t)64 * K);
        Ag += 32; Bg += 32;
        __syncthreads();

        bf16x8 af[4], bfv[4];
#pragma unroll
        for (int m = 0; m < 4; ++m)
            af[m] = *(const bf16x8*)&As[(wr * 64 + m * 16 + fr) * 32 + fq * 8];
#pragma unroll
        for (int n = 0; n < 4; ++n)
            bfv[n] = *(const bf16x8*)&Bs[(wc * 64 + n * 16 + fr) * 32 + fq * 8];
#pragma unroll
        for (int m = 0; m < 4; ++m)
#pragma unroll
            for (int n = 0; n < 4; ++n)
                acc[m][n] = __builtin_amdgcn_mfma_f32_16x16x32_bf16(
                    af[m], bfv[n], acc[m][n], 0, 0, 0);
        __syncthreads();
    }

#pragma unroll
    for (int m = 0; m < 4; ++m) {
#pragma unroll
        for (int n = 0; n < 4; ++n) {
            const int col = bn + wc * 64 + n * 16 + fr;
            const float bv = BIAS ? bias[col] : 0.0f;
#pragma unroll
            for (int j = 0; j < 4; ++j) {
                const int row = bm + wr * 64 + m * 16 + fq * 4 + j;
                float v = acc[m][n][j] + bv;
                if (OUT_BF16)
                    ((ushort_t*)Cc)[(size_t)row * N + col] = f2bf(v);
                else
                    ((float*)Cc)[(size_t)row * N + col] = v;
            }
        }
    }
}

// ---------------------------------------------------------------------------
// MFMA windowed flash attention, v4: ONE barrier per tile (reg-staged K and
// V, V written directly transposed, no global_load_lds anywhere).
// ---------------------------------------------------------------------------
#define MASKNEG (-1e30f)

__global__ __launch_bounds__(512)
void attn_mfma(const ushort_t* __restrict__ qkv, ushort_t* __restrict__ out) {
    __shared__ __align__(16) ushort_t Ks[2][64 * 64];    // 16 KB swizzled
    __shared__ __align__(16) ushort_t Vt[2][64 * 74];    // 18.5 KB V^T padded
    __shared__ __align__(16) ushort_t Ps[8][16 * 72];    // 18 KB per-wave P

    const int tid  = threadIdx.x;
    const int lane = tid & 63;
    const int w    = tid >> 6;
    const int fr   = lane & 15;
    const int fq   = lane >> 4;

    const int blk = blockIdx.x;
    const int qt  = blk & 15;
    const int h   = (blk >> 4) & 15;
    const int b   = blk >> 8;
    const int q0  = qt * 128;

    const ushort_t* base = qkv + (size_t)(b * TT) * QKV_LD + h * (3 * DD);

    const int srow = tid >> 3;          // 0..63 staged row
    const int dcb  = tid & 7;           // dest col-block
    const int cbs  = dcb ^ (srow & 7);  // K source col-block (involution)

    float thK[4];
#pragma unroll
    for (int e = 0; e < 4; ++e)
        thK[e] = __expf(-ROPE_LN * (float)(cbs * 4 + e));

    bf16x8 qf0, qf1;
    {
        const int tq = q0 + w * 16 + fr;
        const ushort_t* qrow = base + (size_t)tq * QKV_LD;
        u16x8 r0 = *(const u16x8*)(qrow + fq * 8);
        u16x8 r1 = *(const u16x8*)(qrow + 32 + fq * 8);
        const float tf = (float)tq;
#pragma unroll
        for (int e = 0; e < 4; ++e) {
            float th0 = __expf(-ROPE_LN * (float)(fq * 4 + e));
            float a0 = tf * th0;
            float s0 = __sinf(a0), c0 = __cosf(a0);
            float x1 = bf2f(r0[2 * e]), x2 = bf2f(r0[2 * e + 1]);
            r0[2 * e]     = f2bf(x1 * c0 - x2 * s0);
            r0[2 * e + 1] = f2bf(x1 * s0 + x2 * c0);
            float th1 = __expf(-ROPE_LN * (float)(16 + fq * 4 + e));
            float a1 = tf * th1;
            float s1 = __sinf(a1), c1 = __cosf(a1);
            float y1 = bf2f(r1[2 * e]), y2 = bf2f(r1[2 * e + 1]);
            r1[2 * e]     = f2bf(y1 * c1 - y2 * s1);
            r1[2 * e + 1] = f2bf(y1 * s1 + y2 * c1);
        }
        qf0 = *(bf16x8*)&r0;
        qf1 = *(bf16x8*)&r1;
    }

    f32x4 oacc[4];
#pragma unroll
    for (int nd = 0; nd < 4; ++nd) oacc[nd] = f32x4{0.f, 0.f, 0.f, 0.f};
    float mj[4], lj[4];
#pragma unroll
    for (int j = 0; j < 4; ++j) { mj[j] = MASKNEG; lj[j] = 0.f; }

    const int kstart = (q0 >= WINW) ? (q0 - WINW) : 0;
    const int ntiles = (q0 + 128 - kstart) >> 6;
    const int qlo = q0 + w * 16;               // wave's q-range [qlo, qlo+15]

    // ---- prologue: stage tile 0 into buf 0 ----
    {
        const ushort_t* rowp = base + (size_t)(kstart + srow) * QKV_LD;
        u16x8 kv = *(const u16x8*)(rowp + DD + cbs * 8);
        u16x8 vv = *(const u16x8*)(rowp + 2 * DD + dcb * 8);
        const float tf = (float)(kstart + srow);
#pragma unroll
        for (int e = 0; e < 4; ++e) {
            float a = tf * thK[e];
            float s = __sinf(a), c = __cosf(a);
            float x1 = bf2f(kv[2 * e]), x2 = bf2f(kv[2 * e + 1]);
            kv[2 * e]     = f2bf(x1 * c - x2 * s);
            kv[2 * e + 1] = f2bf(x1 * s + x2 * c);
        }
        *(u16x8*)&Ks[0][tid * 8] = kv;
#pragma unroll
        for (int e = 0; e < 8; ++e)
            Vt[0][(dcb * 8 + e) * 74 + srow] = vv[e];
    }
    __syncthreads();

    int cur = 0;
    for (int t = 0; t < ntiles; ++t) {
        const int kt0 = kstart + t * 64;
        const bool pf = (t + 1 < ntiles);
        const bool act = (kt0 <= qlo + 15) && (kt0 + 63 >= qlo - WINW);

        // ---- issue next tile's K,V loads (consumed late) ----
        u16x8 kpre, vpre;
        if (pf) {
            const ushort_t* rowp = base + (size_t)(kt0 + 64 + srow) * QKV_LD;
            kpre = *(const u16x8*)(rowp + DD + cbs * 8);
            vpre = *(const u16x8*)(rowp + 2 * DD + dcb * 8);
        }

        if (act) {
            // ---- QK^T with swizzled K reads ----
            f32x4 s[4];
#pragma unroll
            for (int n = 0; n < 4; ++n) {
                const int krow = n * 16 + fr;
                bf16x8 kb0 = *(const bf16x8*)&Ks[cur][krow * 64 + ((fq ^ (krow & 7)) * 8)];
                bf16x8 kb1 = *(const bf16x8*)&Ks[cur][krow * 64 + (((fq + 4) ^ (krow & 7)) * 8)];
                f32x4 z = f32x4{0.f, 0.f, 0.f, 0.f};
                z = __builtin_amdgcn_mfma_f32_16x16x32_bf16(qf0, kb0, z, 0, 0, 0);
                s[n] = __builtin_amdgcn_mfma_f32_16x16x32_bf16(qf1, kb1, z, 0, 0, 0);
            }

            // ---- mask + scale; per-row tile max ----
            float pmax[4];
#pragma unroll
            for (int j = 0; j < 4; ++j) pmax[j] = MASKNEG;
#pragma unroll
            for (int n = 0; n < 4; ++n) {
                const int key = kt0 + n * 16 + fr;
#pragma unroll
                for (int j = 0; j < 4; ++j) {
                    const int qi = qlo + fq * 4 + j;
                    const bool ok = (key <= qi) && (key >= qi - WINW);
                    float sv = ok ? s[n][j] * 0.125f : MASKNEG;
                    s[n][j] = sv;
                    pmax[j] = fmaxf(pmax[j], sv);
                }
            }
#pragma unroll
            for (int off = 1; off < 16; off <<= 1)
#pragma unroll
                for (int j = 0; j < 4; ++j)
                    pmax[j] = fmaxf(pmax[j], __shfl_xor(pmax[j], off));

            // ---- online softmax update + write P ----
            float tl[4] = {0.f, 0.f, 0.f, 0.f};
#pragma unroll
            for (int j = 0; j < 4; ++j) {
                float mnew = fmaxf(mj[j], pmax[j]);
                float alpha = (mnew <= -1e29f) ? 1.0f : __expf(mj[j] - mnew);
                mj[j] = mnew;
                lj[j] *= alpha;
#pragma unroll
                for (int nd = 0; nd < 4; ++nd) oacc[nd][j] *= alpha;
            }
#pragma unroll
            for (int n = 0; n < 4; ++n) {
#pragma unroll
                for (int j = 0; j < 4; ++j) {
                    float sv = s[n][j];
                    float p = (sv <= -1e29f) ? 0.f : __expf(sv - mj[j]);
                    tl[j] += p;
                    Ps[w][(fq * 4 + j) * 72 + n * 16 + fr] = f2bf(p);
                }
            }
#pragma unroll
            for (int off = 1; off < 16; off <<= 1)
#pragma unroll
                for (int j = 0; j < 4; ++j)
                    tl[j] += __shfl_xor(tl[j], off);
#pragma unroll
            for (int j = 0; j < 4; ++j) lj[j] += tl[j];
        }

        // ---- write next buffers (rope K; direct-transpose V) ----
        if (pf) {
            const float tf = (float)(kt0 + 64 + srow);
#pragma unroll
            for (int e = 0; e < 4; ++e) {
                float a = tf * thK[e];
                float s2 = __sinf(a), c2 = __cosf(a);
                float x1 = bf2f(kpre[2 * e]), x2 = bf2f(kpre[2 * e + 1]);
                kpre[2 * e]     = f2bf(x1 * c2 - x2 * s2);
                kpre[2 * e + 1] = f2bf(x1 * s2 + x2 * c2);
            }
            *(u16x8*)&Ks[cur ^ 1][tid * 8] = kpre;
#pragma unroll
            for (int e = 0; e < 8; ++e)
                Vt[cur ^ 1][(dcb * 8 + e) * 74 + srow] = vpre[e];
        }

        if (act) {
            // ---- PV: A = P (LDS bounce), B = Vt[cur] ----
            bf16x8 pa0 = *(const bf16x8*)&Ps[w][fr * 72 + fq * 8];
            bf16x8 pa1 = *(const bf16x8*)&Ps[w][fr * 72 + 32 + fq * 8];
#pragma unroll
            for (int nd = 0; nd < 4; ++nd) {
                bf16x8 vb0 = *(const bf16x8*)&Vt[cur][(nd * 16 + fr) * 74 + fq * 8];
                bf16x8 vb1 = *(const bf16x8*)&Vt[cur][(nd * 16 + fr) * 74 + 32 + fq * 8];
                oacc[nd] = __builtin_amdgcn_mfma_f32_16x16x32_bf16(pa0, vb0, oacc[nd], 0, 0, 0);
                oacc[nd] = __builtin_amdgcn_mfma_f32_16x16x32_bf16(pa1, vb1, oacc[nd], 0, 0, 0);
            }
        }

        __syncthreads();   // the single per-tile barrier
        cur ^= 1;
    }

    // ---- epilogue ----
#pragma unroll
    for (int nd = 0; nd < 4; ++nd) {
#pragma unroll
        for (int j = 0; j < 4; ++j) {
            const int qi = qlo + fq * 4 + j;
            out[(size_t)(b * TT + qi) * CC + h * DD + nd * 16 + fr] =
                f2bf(oacc[nd][j] / lj[j]);
        }
    }
}

// ---------------------------------------------------------------------------
extern "C" void kernel_launch(void* const* d_in, const int* in_sizes, int n_in,
                              void* d_out, int out_size, void* d_ws, size_t ws_size,
                              hipStream_t stream) {
    const float* x     = (const float*)d_in[0];
    const float* w_qkv = (const float*)d_in[1];
    const float* w_out = (const float*)d_in[2];
    const float* b_out = (const float*)d_in[3];
    float* out = (float*)d_out;

    ushort_t* qkv_b  = (ushort_t*)d_ws;
    ushort_t* attn_b = qkv_b  + (size_t)MROWS * NQKV;
    ushort_t* xb     = attn_b + (size_t)MROWS * CC;
    ushort_t* wqb    = xb     + (size_t)MROWS * CC;
    ushort_t* wob    = wqb    + (size_t)NQKV * CC;

    // 0) one fused conversion pass
    convert_all<<<(NX + NQ + NO) / 1024, 256, 0, stream>>>(
        x, w_qkv, w_out, xb, wqb, wob);

    // 1) qkv = x @ w_qkv^T (bf16 out) — 8-phase 256^2 schedule
    gemm1_8phase<<<dim3(NQKV / 256, MROWS / 256), 512, 0, stream>>>(
        xb, wqb, qkv_b);

    // 2) windowed attention with fused RoPE -> attn_b
    attn_mfma<<<BB * HH * (TT / 128), 512, 0, stream>>>(qkv_b, attn_b);

    // 3) out = attn @ w_out^T + b_out  (fp32 out) — m97 structure + swizzle
    gemm_nt_mfma<true, false><<<dim3(CC / 128, MROWS / 128), 256, 0, stream>>>(
        attn_b, wob, b_out, out, MROWS, CC, CC);
}